// Round 1
// baseline (1254.288 us; speedup 1.0000x reference)
//
#include <hip/hip_runtime.h>
#include <cstdint>
#include <cstddef>

#define I_DIM 1024
#define O_DIM 1024
#define B_DIM 128
#define T_DIM 100
#define ROWS (B_DIM * T_DIM)  // 12800

// ---------------------------------------------------------------------------
// norm[o] = sum_a w[a][o]^2 (f64); inv_norm[o] = 1/(norm + 1e-8)
// ---------------------------------------------------------------------------
__global__ void norm_kernel(const float* __restrict__ w,
                            double* __restrict__ inv_norm) {
  int o = blockIdx.x * blockDim.x + threadIdx.x;  // grid 4 x 256 = 1024
  double s = 0.0;
  for (int a = 0; a < I_DIM; ++a) {
    double t = (double)w[(size_t)a * O_DIM + o];
    s += t * t;
  }
  inv_norm[o] = 1.0 / (s + 1e-8);
}

// ---------------------------------------------------------------------------
// M[i][o] = (1-beta)*v[i][o] - beta * sum_a w[a][i]*w[a][o]   (f64)
// 64x64 tile per WG, 256 threads, 4x4 per thread, BK=16. Grid (16,16).
// ---------------------------------------------------------------------------
__global__ __launch_bounds__(256) void mbuild_kernel(
    const float* __restrict__ w, const float* __restrict__ v,
    const float* __restrict__ beta_p, double* __restrict__ M) {
  __shared__ __align__(16) float Wi[16 * 68];  // pad stride 68 floats
  __shared__ __align__(16) float Wo[16 * 68];
  const int tid = threadIdx.x;
  const int tx = tid & 15, ty = tid >> 4;
  const int i0 = blockIdx.y * 64, o0 = blockIdx.x * 64;
  double acc[4][4] = {};
  for (int a0 = 0; a0 < I_DIM; a0 += 16) {
    {  // stage both tiles: 16x64 floats each = 256 float4; one per thread each
      int kk = tid >> 4, c4 = tid & 15;
      *(float4*)&Wi[kk * 68 + c4 * 4] =
          *(const float4*)&w[(size_t)(a0 + kk) * O_DIM + i0 + c4 * 4];
      *(float4*)&Wo[kk * 68 + c4 * 4] =
          *(const float4*)&w[(size_t)(a0 + kk) * O_DIM + o0 + c4 * 4];
    }
    __syncthreads();
#pragma unroll
    for (int kk = 0; kk < 16; ++kk) {
      float4 av = *(const float4*)&Wi[kk * 68 + ty * 4];
      float4 bv = *(const float4*)&Wo[kk * 68 + tx * 4];
      double ad[4] = {(double)av.x, (double)av.y, (double)av.z, (double)av.w};
      double bd[4] = {(double)bv.x, (double)bv.y, (double)bv.z, (double)bv.w};
#pragma unroll
      for (int r = 0; r < 4; ++r)
#pragma unroll
        for (int c = 0; c < 4; ++c) acc[r][c] += ad[r] * bd[c];
    }
    __syncthreads();
  }
  const double beta = (double)beta_p[0];
  const double ombeta = 1.0 - beta;
#pragma unroll
  for (int r = 0; r < 4; ++r) {
    int i = i0 + ty * 4 + r;
#pragma unroll
    for (int c = 0; c < 4; ++c) {
      int o = o0 + tx * 4 + c;
      M[(size_t)i * O_DIM + o] =
          ombeta * (double)v[(size_t)i * O_DIM + o] - beta * acc[r][c];
    }
  }
}

// ---------------------------------------------------------------------------
// h[row][o] = sum_a x[row][a] * w[a][o], f64 accumulate, f32 store.
// 128x128 tile per WG, 256 threads, 8x8 per thread (2x2 blocks of 4), BK=16.
// Grid (8, 100). LDS stays f32 (cvt at use) to keep LDS BW at ~50% while the
// f64 FMA pipe is the bottleneck.
// ---------------------------------------------------------------------------
__global__ __launch_bounds__(256, 2) void hgemm_kernel(
    const float* __restrict__ x, const float* __restrict__ w,
    float* __restrict__ h) {
  __shared__ __align__(16) float As[16 * 132];  // k-major, pad stride 132
  __shared__ __align__(16) float Bs[16 * 132];
  const int tid = threadIdx.x;
  const int tx = tid & 15, ty = tid >> 4;
  const int row0 = blockIdx.y * 128, col0 = blockIdx.x * 128;
  double acc[8][8] = {};
  for (int a0 = 0; a0 < I_DIM; a0 += 16) {
    // stage A with transpose to k-major: 128 rows x 16 k
#pragma unroll
    for (int e = tid; e < 2048; e += 256) {
      int r = e >> 4, kk = e & 15;  // 16 consecutive lanes = 64B row chunk
      As[kk * 132 + r] = x[(size_t)(row0 + r) * I_DIM + a0 + kk];
    }
    // stage B: 16 k-rows x 128 cols, float4
#pragma unroll
    for (int e4 = tid; e4 < 512; e4 += 256) {
      int kk = e4 >> 5, c4 = e4 & 31;
      *(float4*)&Bs[kk * 132 + c4 * 4] =
          *(const float4*)&w[(size_t)(a0 + kk) * O_DIM + col0 + c4 * 4];
    }
    __syncthreads();
#pragma unroll
    for (int kk = 0; kk < 16; ++kk) {
      float4 a0v = *(const float4*)&As[kk * 132 + ty * 4];
      float4 a1v = *(const float4*)&As[kk * 132 + 64 + ty * 4];
      float4 b0v = *(const float4*)&Bs[kk * 132 + tx * 4];
      float4 b1v = *(const float4*)&Bs[kk * 132 + 64 + tx * 4];
      double a[8] = {(double)a0v.x, (double)a0v.y, (double)a0v.z, (double)a0v.w,
                     (double)a1v.x, (double)a1v.y, (double)a1v.z, (double)a1v.w};
      double b[8] = {(double)b0v.x, (double)b0v.y, (double)b0v.z, (double)b0v.w,
                     (double)b1v.x, (double)b1v.y, (double)b1v.z, (double)b1v.w};
#pragma unroll
      for (int r = 0; r < 8; ++r)
#pragma unroll
        for (int c = 0; c < 8; ++c) acc[r][c] += a[r] * b[c];
    }
    __syncthreads();
  }
#pragma unroll
  for (int rb = 0; rb < 2; ++rb)
#pragma unroll
    for (int r = 0; r < 4; ++r) {
      int row = row0 + rb * 64 + ty * 4 + r;
#pragma unroll
      for (int cb = 0; cb < 2; ++cb) {
        int col = col0 + cb * 64 + tx * 4;
        float4 val = make_float4((float)acc[rb * 4 + r][cb * 4 + 0],
                                 (float)acc[rb * 4 + r][cb * 4 + 1],
                                 (float)acc[rb * 4 + r][cb * 4 + 2],
                                 (float)acc[rb * 4 + r][cb * 4 + 3]);
        *(float4*)&h[(size_t)row * O_DIM + col] = val;
      }
    }
}

// ---------------------------------------------------------------------------
// Per-batch scan: one WG per batch (grid 128, block 256, 4 neurons/thread).
// mem (f64) in registers; spike index lists double-buffered in LDS; lateral
// term = gather of M rows for fired neurons (spk is binary -> no matmul).
// counts[t] (global, ws) accumulates spikes per step across batches.
// ---------------------------------------------------------------------------
__global__ __launch_bounds__(256) void scan_kernel(
    const float* __restrict__ h, const double* __restrict__ M,
    const double* __restrict__ inv_norm, const float* __restrict__ bvec,
    const float* __restrict__ beta_p, float* __restrict__ out,
    int* __restrict__ counts) {
  __shared__ unsigned short lists[2][1024];
  __shared__ int cnts[2];
  const int b = blockIdx.x, tid = threadIdx.x;
  const double beta = (double)beta_p[0];
  const double ombeta = 1.0 - beta;
  double mem[4] = {0.0, 0.0, 0.0, 0.0};
  double inv[4], bth[4];
  int o[4];
#pragma unroll
  for (int j = 0; j < 4; ++j) {
    o[j] = tid + j * 256;
    inv[j] = inv_norm[o[j]];
    bth[j] = (double)bvec[o[j]];
  }
  if (tid < 2) cnts[tid] = 0;
  __syncthreads();
  const float* hb = h + (size_t)b * T_DIM * O_DIM;
  float* ob = out + (size_t)b * T_DIM * O_DIM;
  for (int t = 0; t < T_DIM; ++t) {
    const int p = t & 1, np = p ^ 1;
    if (tid == 0) cnts[np] = 0;
    __syncthreads();  // prev list complete + reset visible
    double lat[4] = {0.0, 0.0, 0.0, 0.0};
    const int k = cnts[p];
    for (int n = 0; n < k; ++n) {
      int i = lists[p][n];
      const double* Mrow = M + (size_t)i * O_DIM;
#pragma unroll
      for (int j = 0; j < 4; ++j) lat[j] += Mrow[o[j]];
    }
#pragma unroll
    for (int j = 0; j < 4; ++j) {
      double hv = (double)hb[(size_t)t * O_DIM + o[j]];
      mem[j] = mem[j] * beta + hv * ombeta + lat[j];
      double mthr = mem[j] * inv[j] - bth[j];
      bool s = mthr > 0.0;
      ob[(size_t)t * O_DIM + o[j]] = s ? 1.0f : 0.0f;
      if (s) {
        int pos = atomicAdd(&cnts[np], 1);
        lists[np][pos] = (unsigned short)o[j];
      }
    }
    __syncthreads();  // new list complete
    if (tid == 0) atomicAdd(&counts[t], cnts[np]);
  }
}

// ---------------------------------------------------------------------------
// loss = 0.5 * total_spikes / (B*T*O);  spread = max_t counts[t] / (B*O)
// ---------------------------------------------------------------------------
__global__ void finalize_kernel(const int* __restrict__ counts,
                                float* __restrict__ out) {
  if (threadIdx.x == 0) {
    long long total = 0;
    int mx = 0;
    for (int t = 0; t < T_DIM; ++t) {
      total += counts[t];
      if (counts[t] > mx) mx = counts[t];
    }
    const double N = (double)B_DIM * T_DIM * O_DIM;  // 13107200
    out[(size_t)B_DIM * T_DIM * O_DIM] = (float)(0.5 * (double)total / N);
    out[(size_t)B_DIM * T_DIM * O_DIM + 1] =
        (float)((double)mx / (double)(B_DIM * O_DIM));
  }
}

extern "C" void kernel_launch(void* const* d_in, const int* in_sizes, int n_in,
                              void* d_out, int out_size, void* d_ws,
                              size_t ws_size, hipStream_t stream) {
  const float* x = (const float*)d_in[0];     // [128,100,1024]
  const float* w = (const float*)d_in[1];     // [1024,1024]
  const float* v = (const float*)d_in[2];     // [1024,1024]
  const float* beta = (const float*)d_in[3];  // [1]
  const float* b = (const float*)d_in[4];     // [1024]
  // d_in[5] = sigma: unused in forward (only in custom VJP backward)
  float* out = (float*)d_out;

  char* ws = (char*)d_ws;
  // ws layout: M f64 8MB | h f32 52.4MB | inv_norm f64 8KB | counts 400B
  double* M = (double*)ws;
  float* h = (float*)(ws + 8388608);
  double* invn = (double*)(ws + 8388608 + 52428800);
  int* counts = (int*)(ws + 8388608 + 52428800 + 8192);

  hipLaunchKernelGGL(norm_kernel, dim3(4), dim3(256), 0, stream, w, invn);
  hipLaunchKernelGGL(mbuild_kernel, dim3(16, 16), dim3(256), 0, stream, w, v,
                     beta, M);
  hipLaunchKernelGGL(hgemm_kernel, dim3(8, 100), dim3(256), 0, stream, x, w, h);
  hipMemsetAsync(counts, 0, T_DIM * sizeof(int), stream);
  hipLaunchKernelGGL(scan_kernel, dim3(128), dim3(256), 0, stream, h, M, invn,
                     b, beta, out, counts);
  hipLaunchKernelGGL(finalize_kernel, dim3(1), dim3(64), 0, stream, counts,
                     out);
}

// Round 2
// 788.547 us; speedup vs baseline: 1.5906x; 1.5906x over previous
//
#include <hip/hip_runtime.h>
#include <cstdint>
#include <cstddef>

#define I_DIM 1024
#define O_DIM 1024
#define B_DIM 128
#define T_DIM 100

// ---------------------------------------------------------------------------
// norm[o] = sum_a w[a][o]^2 (f64); inv_norm[o] = 1/(norm + 1e-8)
// Kept in f64: norm error multiplies mem (~1.0 scale) directly, tightest
// precision budget in the whole pipeline.
// ---------------------------------------------------------------------------
__global__ void norm_kernel(const float* __restrict__ w,
                            double* __restrict__ inv_norm) {
  int o = blockIdx.x * 64 + threadIdx.x;  // grid 16 x 64
  double s = 0.0;
  for (int a = 0; a < I_DIM; ++a) {
    double t = (double)w[(size_t)a * O_DIM + o];
    s += t * t;
  }
  inv_norm[o] = 1.0 / (s + 1e-8);
}

// ---------------------------------------------------------------------------
// M[i][o] = (1-beta)*v[i][o] - beta * sum_a w[a][i]*w[a][o]   (f32)
// f32 is fine here: M only enters mem via the ~1 fired spike per step,
// error ~6e-8 absolute. 64x64 tile, 256 thr, 4x4/thread, BK=16.
// ---------------------------------------------------------------------------
__global__ __launch_bounds__(256) void mbuild_kernel(
    const float* __restrict__ w, const float* __restrict__ v,
    const float* __restrict__ beta_p, float* __restrict__ M) {
  __shared__ __align__(16) float Wi[16 * 68];
  __shared__ __align__(16) float Wo[16 * 68];
  const int tid = threadIdx.x;
  const int tx = tid & 15, ty = tid >> 4;
  const int i0 = blockIdx.y * 64, o0 = blockIdx.x * 64;
  float acc[4][4] = {};
  for (int a0 = 0; a0 < I_DIM; a0 += 16) {
    {
      int kk = tid >> 4, c4 = tid & 15;
      *(float4*)&Wi[kk * 68 + c4 * 4] =
          *(const float4*)&w[(size_t)(a0 + kk) * O_DIM + i0 + c4 * 4];
      *(float4*)&Wo[kk * 68 + c4 * 4] =
          *(const float4*)&w[(size_t)(a0 + kk) * O_DIM + o0 + c4 * 4];
    }
    __syncthreads();
#pragma unroll
    for (int kk = 0; kk < 16; ++kk) {
      float4 av = *(const float4*)&Wi[kk * 68 + ty * 4];
      float4 bv = *(const float4*)&Wo[kk * 68 + tx * 4];
      float a[4] = {av.x, av.y, av.z, av.w};
      float b[4] = {bv.x, bv.y, bv.z, bv.w};
#pragma unroll
      for (int r = 0; r < 4; ++r)
#pragma unroll
        for (int c = 0; c < 4; ++c) acc[r][c] += a[r] * b[c];
    }
    __syncthreads();
  }
  const float beta = beta_p[0];
  const float ombeta = 1.0f - beta;
#pragma unroll
  for (int r = 0; r < 4; ++r) {
    int i = i0 + ty * 4 + r;
#pragma unroll
    for (int c = 0; c < 4; ++c) {
      int o = o0 + tx * 4 + c;
      M[(size_t)i * O_DIM + o] =
          ombeta * v[(size_t)i * O_DIM + o] - beta * acc[r][c];
    }
  }
}

// ---------------------------------------------------------------------------
// h[row][o] = sum_a x[row][a] * w[a][o]
// f32 FMA pipe (157 TF) with BK=32 f32 chunk accumulation drained to an
// f64 master each chunk: delta_h ~ 1.7e-7, ~50x tighter than pure f32.
// 128x128 tile, 256 thr, 8x8/thread. Grid (8,100).
// Regs: 64 f32 cacc + 128 f64 macc + frags ~ 230 -> 2 waves/SIMD.
// ---------------------------------------------------------------------------
__global__ __launch_bounds__(256, 2) void hgemm_kernel(
    const float* __restrict__ x, const float* __restrict__ w,
    float* __restrict__ h) {
  __shared__ __align__(16) float As[32 * 132];  // k-major, pad stride 132
  __shared__ __align__(16) float Bs[32 * 132];
  const int tid = threadIdx.x;
  const int tx = tid & 15, ty = tid >> 4;
  const int row0 = blockIdx.y * 128, col0 = blockIdx.x * 128;
  double macc[8][8] = {};
  for (int a0 = 0; a0 < I_DIM; a0 += 32) {
    // stage A with transpose to k-major: 128 rows x 32 k, float4 global loads
#pragma unroll
    for (int e4 = tid; e4 < 1024; e4 += 256) {
      int r = e4 >> 3, kq = (e4 & 7) * 4;
      float4 val = *(const float4*)&x[(size_t)(row0 + r) * I_DIM + a0 + kq];
      As[(kq + 0) * 132 + r] = val.x;
      As[(kq + 1) * 132 + r] = val.y;
      As[(kq + 2) * 132 + r] = val.z;
      As[(kq + 3) * 132 + r] = val.w;
    }
    // stage B: 32 k-rows x 128 cols, float4
#pragma unroll
    for (int e4 = tid; e4 < 1024; e4 += 256) {
      int kk = e4 >> 5, c4 = (e4 & 31) * 4;
      *(float4*)&Bs[kk * 132 + c4] =
          *(const float4*)&w[(size_t)(a0 + kk) * O_DIM + col0 + c4];
    }
    __syncthreads();
    float cacc[8][8] = {};
#pragma unroll 8
    for (int kk = 0; kk < 32; ++kk) {
      float4 a0v = *(const float4*)&As[kk * 132 + ty * 4];
      float4 a1v = *(const float4*)&As[kk * 132 + 64 + ty * 4];
      float4 b0v = *(const float4*)&Bs[kk * 132 + tx * 4];
      float4 b1v = *(const float4*)&Bs[kk * 132 + 64 + tx * 4];
      float a[8] = {a0v.x, a0v.y, a0v.z, a0v.w, a1v.x, a1v.y, a1v.z, a1v.w};
      float b[8] = {b0v.x, b0v.y, b0v.z, b0v.w, b1v.x, b1v.y, b1v.z, b1v.w};
#pragma unroll
      for (int r = 0; r < 8; ++r)
#pragma unroll
        for (int c = 0; c < 8; ++c) cacc[r][c] += a[r] * b[c];
    }
#pragma unroll
    for (int r = 0; r < 8; ++r)
#pragma unroll
      for (int c = 0; c < 8; ++c) macc[r][c] += (double)cacc[r][c];
    __syncthreads();
  }
#pragma unroll
  for (int rb = 0; rb < 2; ++rb)
#pragma unroll
    for (int r = 0; r < 4; ++r) {
      int row = row0 + rb * 64 + ty * 4 + r;
#pragma unroll
      for (int cb = 0; cb < 2; ++cb) {
        int col = col0 + cb * 64 + tx * 4;
        float4 val = make_float4((float)macc[rb * 4 + r][cb * 4 + 0],
                                 (float)macc[rb * 4 + r][cb * 4 + 1],
                                 (float)macc[rb * 4 + r][cb * 4 + 2],
                                 (float)macc[rb * 4 + r][cb * 4 + 3]);
        *(float4*)&h[(size_t)row * O_DIM + col] = val;
      }
    }
}

// ---------------------------------------------------------------------------
// Per-batch scan: one WG per batch. mem f64 in regs; binary spikes -> the
// lateral matmuls collapse to a gather of M rows for fired neurons.
// h for step t+1 is prefetched while step t's gather/update runs.
// ---------------------------------------------------------------------------
__global__ __launch_bounds__(256) void scan_kernel(
    const float* __restrict__ h, const float* __restrict__ M,
    const double* __restrict__ inv_norm, const float* __restrict__ bvec,
    const float* __restrict__ beta_p, float* __restrict__ out,
    int* __restrict__ counts) {
  __shared__ unsigned short lists[2][1024];
  __shared__ int cnts[2];
  const int b = blockIdx.x, tid = threadIdx.x;
  const double beta = (double)beta_p[0];
  const double ombeta = 1.0 - beta;
  double mem[4] = {0.0, 0.0, 0.0, 0.0};
  double inv[4], bth[4];
  int o[4];
#pragma unroll
  for (int j = 0; j < 4; ++j) {
    o[j] = tid + j * 256;
    inv[j] = inv_norm[o[j]];
    bth[j] = (double)bvec[o[j]];
  }
  if (tid < 2) cnts[tid] = 0;
  __syncthreads();
  const float* hb = h + (size_t)b * T_DIM * O_DIM;
  float* ob = out + (size_t)b * T_DIM * O_DIM;
  float hv[4];
#pragma unroll
  for (int j = 0; j < 4; ++j) hv[j] = hb[o[j]];
  for (int t = 0; t < T_DIM; ++t) {
    const int p = t & 1, np = p ^ 1;
    if (tid == 0) cnts[np] = 0;
    __syncthreads();  // prev list complete + reset visible
    // prefetch next step's h while we gather/update
    float hvn[4] = {0.f, 0.f, 0.f, 0.f};
    if (t + 1 < T_DIM) {
#pragma unroll
      for (int j = 0; j < 4; ++j) hvn[j] = hb[(size_t)(t + 1) * O_DIM + o[j]];
    }
    double lat[4] = {0.0, 0.0, 0.0, 0.0};
    const int k = cnts[p];
    for (int n = 0; n < k; ++n) {
      int i = lists[p][n];
      const float* Mrow = M + (size_t)i * O_DIM;
#pragma unroll
      for (int j = 0; j < 4; ++j) lat[j] += (double)Mrow[o[j]];
    }
#pragma unroll
    for (int j = 0; j < 4; ++j) {
      mem[j] = mem[j] * beta + (double)hv[j] * ombeta + lat[j];
      double mthr = mem[j] * inv[j] - bth[j];
      bool s = mthr > 0.0;
      ob[(size_t)t * O_DIM + o[j]] = s ? 1.0f : 0.0f;
      if (s) {
        int pos = atomicAdd(&cnts[np], 1);
        lists[np][pos] = (unsigned short)o[j];
      }
    }
#pragma unroll
    for (int j = 0; j < 4; ++j) hv[j] = hvn[j];
    __syncthreads();  // new list complete
    if (tid == 0) atomicAdd(&counts[t], cnts[np]);
  }
}

// ---------------------------------------------------------------------------
// loss = 0.5 * total_spikes / (B*T*O);  spread = max_t counts[t] / (B*O)
// Exact integer arithmetic from per-step counts.
// ---------------------------------------------------------------------------
__global__ void finalize_kernel(const int* __restrict__ counts,
                                float* __restrict__ out) {
  if (threadIdx.x == 0) {
    long long total = 0;
    int mx = 0;
    for (int t = 0; t < T_DIM; ++t) {
      total += counts[t];
      if (counts[t] > mx) mx = counts[t];
    }
    const double N = (double)B_DIM * T_DIM * O_DIM;
    out[(size_t)B_DIM * T_DIM * O_DIM] = (float)(0.5 * (double)total / N);
    out[(size_t)B_DIM * T_DIM * O_DIM + 1] =
        (float)((double)mx / (double)(B_DIM * O_DIM));
  }
}

extern "C" void kernel_launch(void* const* d_in, const int* in_sizes, int n_in,
                              void* d_out, int out_size, void* d_ws,
                              size_t ws_size, hipStream_t stream) {
  const float* x = (const float*)d_in[0];     // [128,100,1024]
  const float* w = (const float*)d_in[1];     // [1024,1024]
  const float* v = (const float*)d_in[2];     // [1024,1024]
  const float* beta = (const float*)d_in[3];  // [1]
  const float* b = (const float*)d_in[4];     // [1024]
  // d_in[5] = sigma: forward-unused (only in the surrogate backward)
  float* out = (float*)d_out;

  char* ws = (char*)d_ws;
  // ws layout: M f32 4MB | h f32 50MB | inv_norm f64 8KB | counts 400B
  float* M = (float*)ws;
  float* h = (float*)(ws + 4194304);
  double* invn = (double*)(ws + 4194304 + 52428800);
  int* counts = (int*)(ws + 4194304 + 52428800 + 8192);

  hipLaunchKernelGGL(norm_kernel, dim3(16), dim3(64), 0, stream, w, invn);
  hipLaunchKernelGGL(mbuild_kernel, dim3(16, 16), dim3(256), 0, stream, w, v,
                     beta, M);
  hipLaunchKernelGGL(hgemm_kernel, dim3(8, 100), dim3(256), 0, stream, x, w, h);
  hipMemsetAsync(counts, 0, T_DIM * sizeof(int), stream);
  hipLaunchKernelGGL(scan_kernel, dim3(128), dim3(256), 0, stream, h, M, invn,
                     b, beta, out, counts);
  hipLaunchKernelGGL(finalize_kernel, dim3(1), dim3(64), 0, stream, counts,
                     out);
}

// Round 3
// 414.050 us; speedup vs baseline: 3.0293x; 1.9045x over previous
//
#include <hip/hip_runtime.h>
#include <cstdint>
#include <cstddef>

#define I_DIM 1024
#define O_DIM 1024
#define B_DIM 128
#define T_DIM 100
#define ROWP 40  // LDS row pitch in ushorts (80 B): breaks 16-bank aliasing,
                 // keeps 16B alignment for ds_read_b128 (80 % 16 == 0)

typedef __attribute__((ext_vector_type(8))) __bf16 bf16x8;
typedef __attribute__((ext_vector_type(16))) float f32x16;

// round-to-nearest-even f32 -> bf16 bits
__device__ __forceinline__ unsigned short bf16rn(float x) {
  unsigned u = __float_as_uint(x);
  unsigned r = u + 0x7FFFu + ((u >> 16) & 1u);
  return (unsigned short)(r >> 16);
}
// two-term split: x ~= hi + lo with |x - hi - lo| <= 2^-16 |x|
__device__ __forceinline__ void split2(float x, unsigned short& h,
                                       unsigned short& l) {
  h = bf16rn(x);
  float hf = __uint_as_float(((unsigned)h) << 16);
  l = bf16rn(x - hf);
}

// ---------------------------------------------------------------------------
// wT_hi/lo[o][a] = split2(w[a][o]) — one-time transpose+split so the GEMM
// B-staging is a straight bf16 copy (R2's in-loop scalar transpose was the
// staging bottleneck). 64x64 tiles via LDS.
// ---------------------------------------------------------------------------
__global__ __launch_bounds__(256) void split_wT_kernel(
    const float* __restrict__ w, unsigned short* __restrict__ wTh,
    unsigned short* __restrict__ wTl) {
  __shared__ float tile[64][65];
  const int a0 = blockIdx.y * 64, o0 = blockIdx.x * 64;
  const int tid = threadIdx.x;
  const int tr = tid >> 4, tc4 = (tid & 15) * 4;
#pragma unroll
  for (int rr = 0; rr < 64; rr += 16) {
    float4 v = *(const float4*)&w[(size_t)(a0 + tr + rr) * O_DIM + o0 + tc4];
    tile[tr + rr][tc4 + 0] = v.x;
    tile[tr + rr][tc4 + 1] = v.y;
    tile[tr + rr][tc4 + 2] = v.z;
    tile[tr + rr][tc4 + 3] = v.w;
  }
  __syncthreads();
#pragma unroll
  for (int rr = 0; rr < 64; rr += 16) {
    int o = o0 + tr + rr;
    unsigned short h[4], l[4];
#pragma unroll
    for (int j = 0; j < 4; ++j) split2(tile[tc4 + j][tr + rr], h[j], l[j]);
    *(ushort4*)&wTh[(size_t)o * I_DIM + a0 + tc4] =
        make_ushort4(h[0], h[1], h[2], h[3]);
    *(ushort4*)&wTl[(size_t)o * I_DIM + a0 + tc4] =
        make_ushort4(l[0], l[1], l[2], l[3]);
  }
}

// ---------------------------------------------------------------------------
// norm[o] = sum_a w[a][o]^2 (f64) — tightest precision budget, keep exact.
// ---------------------------------------------------------------------------
__global__ void norm_kernel(const float* __restrict__ w,
                            double* __restrict__ inv_norm) {
  int o = blockIdx.x * 64 + threadIdx.x;
  double s = 0.0;
  for (int a = 0; a < I_DIM; ++a) {
    double t = (double)w[(size_t)a * O_DIM + o];
    s += t * t;
  }
  inv_norm[o] = 1.0 / (s + 1e-8);
}

// ---------------------------------------------------------------------------
// M[i][o] = (1-beta)*v[i][o] - beta * sum_a w[a][i]*w[a][o]
// MFMA bf16x2 3-pass; both operands are wT rows (A[m=i][k=a]=wT[i][a],
// B[n=o][k=a]=wT[o][a]). 128x128 WG tile, 2x2 waves of 2x2 32x32 tiles.
// ---------------------------------------------------------------------------
__global__ __launch_bounds__(256) void mbuild_mfma(
    const unsigned short* __restrict__ wTh,
    const unsigned short* __restrict__ wTl, const float* __restrict__ v,
    const float* __restrict__ beta_p, float* __restrict__ M) {
  __shared__ ushort Ah[128 * ROWP], Al[128 * ROWP];
  __shared__ ushort Bh[128 * ROWP], Bl[128 * ROWP];
  const int tid = threadIdx.x;
  const int i0 = blockIdx.y * 128, o0 = blockIdx.x * 128;
  const int wv = tid >> 6, lane = tid & 63;
  const int wm = wv >> 1, wn = wv & 1;
  const int lm = lane & 31, lkh = lane >> 5;
  f32x16 acc[2][2];
#pragma unroll
  for (int a = 0; a < 2; ++a)
#pragma unroll
    for (int b = 0; b < 2; ++b)
#pragma unroll
      for (int e = 0; e < 16; ++e) acc[a][b][e] = 0.f;
  const int sm = tid >> 1, sko = (tid & 1) * 16;
  for (int a0 = 0; a0 < I_DIM; a0 += 32) {
    const ushort* gAh = wTh + (size_t)(i0 + sm) * I_DIM + a0 + sko;
    const ushort* gAl = wTl + (size_t)(i0 + sm) * I_DIM + a0 + sko;
    const ushort* gBh = wTh + (size_t)(o0 + sm) * I_DIM + a0 + sko;
    const ushort* gBl = wTl + (size_t)(o0 + sm) * I_DIM + a0 + sko;
    *(uint4*)&Ah[sm * ROWP + sko] = ((const uint4*)gAh)[0];
    *(uint4*)&Ah[sm * ROWP + sko + 8] = ((const uint4*)gAh)[1];
    *(uint4*)&Al[sm * ROWP + sko] = ((const uint4*)gAl)[0];
    *(uint4*)&Al[sm * ROWP + sko + 8] = ((const uint4*)gAl)[1];
    *(uint4*)&Bh[sm * ROWP + sko] = ((const uint4*)gBh)[0];
    *(uint4*)&Bh[sm * ROWP + sko + 8] = ((const uint4*)gBh)[1];
    *(uint4*)&Bl[sm * ROWP + sko] = ((const uint4*)gBl)[0];
    *(uint4*)&Bl[sm * ROWP + sko + 8] = ((const uint4*)gBl)[1];
    __syncthreads();
#pragma unroll
    for (int ks = 0; ks < 32; ks += 16) {
      bf16x8 fah[2], fal[2], fbh[2], fbl[2];
#pragma unroll
      for (int t = 0; t < 2; ++t) {
        int aoff = (wm * 64 + t * 32 + lm) * ROWP + ks + lkh * 8;
        fah[t] = *(const bf16x8*)&Ah[aoff];
        fal[t] = *(const bf16x8*)&Al[aoff];
        int boff = (wn * 64 + t * 32 + lm) * ROWP + ks + lkh * 8;
        fbh[t] = *(const bf16x8*)&Bh[boff];
        fbl[t] = *(const bf16x8*)&Bl[boff];
      }
#pragma unroll
      for (int mt = 0; mt < 2; ++mt)
#pragma unroll
        for (int nt = 0; nt < 2; ++nt) {
          acc[mt][nt] = __builtin_amdgcn_mfma_f32_32x32x16_bf16(
              fah[mt], fbh[nt], acc[mt][nt], 0, 0, 0);
          acc[mt][nt] = __builtin_amdgcn_mfma_f32_32x32x16_bf16(
              fah[mt], fbl[nt], acc[mt][nt], 0, 0, 0);
          acc[mt][nt] = __builtin_amdgcn_mfma_f32_32x32x16_bf16(
              fal[mt], fbh[nt], acc[mt][nt], 0, 0, 0);
        }
    }
    __syncthreads();
  }
  const float beta = beta_p[0];
  const float ombeta = 1.0f - beta;
#pragma unroll
  for (int mt = 0; mt < 2; ++mt)
#pragma unroll
    for (int nt = 0; nt < 2; ++nt) {
      int col = o0 + wn * 64 + nt * 32 + lm;
#pragma unroll
      for (int r = 0; r < 16; ++r) {
        int row = i0 + wm * 64 + mt * 32 + (r & 3) + 8 * (r >> 2) + 4 * lkh;
        M[(size_t)row * O_DIM + col] =
            ombeta * v[(size_t)row * O_DIM + col] - beta * acc[mt][nt][r];
      }
    }
}

// ---------------------------------------------------------------------------
// h[row][o] = sum_a x[row][a] * w[a][o]
// bf16x2-split 3-pass MFMA: x split in-kernel during A-staging (row-major,
// no transpose needed); B staged as straight copies of wT_hi/lo.
// 128x128 WG tile, grid (8,100). Per wave/chunk: 24 MFMA : 16 ds_read_b128.
// ---------------------------------------------------------------------------
__global__ __launch_bounds__(256) void hgemm_mfma(
    const float* __restrict__ x, const unsigned short* __restrict__ wTh,
    const unsigned short* __restrict__ wTl, float* __restrict__ h) {
  __shared__ ushort Ah[128 * ROWP], Al[128 * ROWP];
  __shared__ ushort Bh[128 * ROWP], Bl[128 * ROWP];
  const int tid = threadIdx.x;
  const int row0 = blockIdx.y * 128, col0 = blockIdx.x * 128;
  const int wv = tid >> 6, lane = tid & 63;
  const int wm = wv >> 1, wn = wv & 1;
  const int lm = lane & 31, lkh = lane >> 5;
  f32x16 acc[2][2];
#pragma unroll
  for (int a = 0; a < 2; ++a)
#pragma unroll
    for (int b = 0; b < 2; ++b)
#pragma unroll
      for (int e = 0; e < 16; ++e) acc[a][b][e] = 0.f;
  const int sm = tid >> 1, sko = (tid & 1) * 16;
  for (int a0 = 0; a0 < I_DIM; a0 += 32) {
    // A: load f32, split to hi/lo bf16 (no transpose: x is [m][k] row-major)
    const float* gA = x + (size_t)(row0 + sm) * I_DIM + a0 + sko;
#pragma unroll
    for (int i = 0; i < 4; ++i) {
      float4 vx = ((const float4*)gA)[i];
      unsigned short h0, l0, h1, l1, h2, l2, h3, l3;
      split2(vx.x, h0, l0);
      split2(vx.y, h1, l1);
      split2(vx.z, h2, l2);
      split2(vx.w, h3, l3);
      *(ushort4*)&Ah[sm * ROWP + sko + 4 * i] = make_ushort4(h0, h1, h2, h3);
      *(ushort4*)&Al[sm * ROWP + sko + 4 * i] = make_ushort4(l0, l1, l2, l3);
    }
    // B: straight bf16 copy from pre-split wT
    const ushort* gBh = wTh + (size_t)(col0 + sm) * I_DIM + a0 + sko;
    const ushort* gBl = wTl + (size_t)(col0 + sm) * I_DIM + a0 + sko;
    *(uint4*)&Bh[sm * ROWP + sko] = ((const uint4*)gBh)[0];
    *(uint4*)&Bh[sm * ROWP + sko + 8] = ((const uint4*)gBh)[1];
    *(uint4*)&Bl[sm * ROWP + sko] = ((const uint4*)gBl)[0];
    *(uint4*)&Bl[sm * ROWP + sko + 8] = ((const uint4*)gBl)[1];
    __syncthreads();
#pragma unroll
    for (int ks = 0; ks < 32; ks += 16) {
      bf16x8 fah[2], fal[2], fbh[2], fbl[2];
#pragma unroll
      for (int t = 0; t < 2; ++t) {
        int aoff = (wm * 64 + t * 32 + lm) * ROWP + ks + lkh * 8;
        fah[t] = *(const bf16x8*)&Ah[aoff];
        fal[t] = *(const bf16x8*)&Al[aoff];
        int boff = (wn * 64 + t * 32 + lm) * ROWP + ks + lkh * 8;
        fbh[t] = *(const bf16x8*)&Bh[boff];
        fbl[t] = *(const bf16x8*)&Bl[boff];
      }
#pragma unroll
      for (int mt = 0; mt < 2; ++mt)
#pragma unroll
        for (int nt = 0; nt < 2; ++nt) {
          acc[mt][nt] = __builtin_amdgcn_mfma_f32_32x32x16_bf16(
              fah[mt], fbh[nt], acc[mt][nt], 0, 0, 0);
          acc[mt][nt] = __builtin_amdgcn_mfma_f32_32x32x16_bf16(
              fah[mt], fbl[nt], acc[mt][nt], 0, 0, 0);
          acc[mt][nt] = __builtin_amdgcn_mfma_f32_32x32x16_bf16(
              fal[mt], fbh[nt], acc[mt][nt], 0, 0, 0);
        }
    }
    __syncthreads();
  }
  // epilogue: C/D layout col=lane&31, row=(r&3)+8*(r>>2)+4*(lane>>5)
#pragma unroll
  for (int mt = 0; mt < 2; ++mt)
#pragma unroll
    for (int nt = 0; nt < 2; ++nt) {
      int col = col0 + wn * 64 + nt * 32 + lm;
#pragma unroll
      for (int r = 0; r < 16; ++r) {
        int row = row0 + wm * 64 + mt * 32 + (r & 3) + 8 * (r >> 2) + 4 * lkh;
        h[(size_t)row * O_DIM + col] = acc[mt][nt][r];
      }
    }
}

// ---------------------------------------------------------------------------
// Per-batch scan: one WG per batch; binary spikes -> lateral matmul is a
// gather of M rows for fired neurons; mem f64 in regs.
// ---------------------------------------------------------------------------
__global__ __launch_bounds__(256) void scan_kernel(
    const float* __restrict__ h, const float* __restrict__ M,
    const double* __restrict__ inv_norm, const float* __restrict__ bvec,
    const float* __restrict__ beta_p, float* __restrict__ out,
    int* __restrict__ counts) {
  __shared__ unsigned short lists[2][1024];
  __shared__ int cnts[2];
  const int b = blockIdx.x, tid = threadIdx.x;
  const double beta = (double)beta_p[0];
  const double ombeta = 1.0 - beta;
  double mem[4] = {0.0, 0.0, 0.0, 0.0};
  double inv[4], bth[4];
  int o[4];
#pragma unroll
  for (int j = 0; j < 4; ++j) {
    o[j] = tid + j * 256;
    inv[j] = inv_norm[o[j]];
    bth[j] = (double)bvec[o[j]];
  }
  if (tid < 2) cnts[tid] = 0;
  __syncthreads();
  const float* hb = h + (size_t)b * T_DIM * O_DIM;
  float* ob = out + (size_t)b * T_DIM * O_DIM;
  float hv[4];
#pragma unroll
  for (int j = 0; j < 4; ++j) hv[j] = hb[o[j]];
  for (int t = 0; t < T_DIM; ++t) {
    const int p = t & 1, np = p ^ 1;
    if (tid == 0) cnts[np] = 0;
    __syncthreads();
    float hvn[4] = {0.f, 0.f, 0.f, 0.f};
    if (t + 1 < T_DIM) {
#pragma unroll
      for (int j = 0; j < 4; ++j) hvn[j] = hb[(size_t)(t + 1) * O_DIM + o[j]];
    }
    double lat[4] = {0.0, 0.0, 0.0, 0.0};
    const int k = cnts[p];
    for (int n = 0; n < k; ++n) {
      int i = lists[p][n];
      const float* Mrow = M + (size_t)i * O_DIM;
#pragma unroll
      for (int j = 0; j < 4; ++j) lat[j] += (double)Mrow[o[j]];
    }
#pragma unroll
    for (int j = 0; j < 4; ++j) {
      mem[j] = mem[j] * beta + (double)hv[j] * ombeta + lat[j];
      double mthr = mem[j] * inv[j] - bth[j];
      bool s = mthr > 0.0;
      ob[(size_t)t * O_DIM + o[j]] = s ? 1.0f : 0.0f;
      if (s) {
        int pos = atomicAdd(&cnts[np], 1);
        lists[np][pos] = (unsigned short)o[j];
      }
    }
#pragma unroll
    for (int j = 0; j < 4; ++j) hv[j] = hvn[j];
    __syncthreads();
    if (tid == 0) atomicAdd(&counts[t], cnts[np]);
  }
}

__global__ void finalize_kernel(const int* __restrict__ counts,
                                float* __restrict__ out) {
  if (threadIdx.x == 0) {
    long long total = 0;
    int mx = 0;
    for (int t = 0; t < T_DIM; ++t) {
      total += counts[t];
      if (counts[t] > mx) mx = counts[t];
    }
    const double N = (double)B_DIM * T_DIM * O_DIM;
    out[(size_t)B_DIM * T_DIM * O_DIM] = (float)(0.5 * (double)total / N);
    out[(size_t)B_DIM * T_DIM * O_DIM + 1] =
        (float)((double)mx / (double)(B_DIM * O_DIM));
  }
}

extern "C" void kernel_launch(void* const* d_in, const int* in_sizes, int n_in,
                              void* d_out, int out_size, void* d_ws,
                              size_t ws_size, hipStream_t stream) {
  const float* x = (const float*)d_in[0];
  const float* w = (const float*)d_in[1];
  const float* v = (const float*)d_in[2];
  const float* beta = (const float*)d_in[3];
  const float* b = (const float*)d_in[4];
  float* out = (float*)d_out;

  char* ws = (char*)d_ws;
  // M f32 4MB | h f32 50MB | wT_hi 2MB | wT_lo 2MB | inv_norm 8KB | counts
  float* M = (float*)ws;
  float* h = (float*)(ws + 4194304);
  unsigned short* wTh = (unsigned short*)(ws + 4194304 + 52428800);
  unsigned short* wTl = (unsigned short*)(ws + 4194304 + 52428800 + 2097152);
  double* invn = (double*)(ws + 4194304 + 52428800 + 4194304);
  int* counts = (int*)(ws + 4194304 + 52428800 + 4194304 + 8192);

  hipLaunchKernelGGL(split_wT_kernel, dim3(16, 16), dim3(256), 0, stream, w,
                     wTh, wTl);
  hipLaunchKernelGGL(norm_kernel, dim3(16), dim3(64), 0, stream, w, invn);
  hipLaunchKernelGGL(mbuild_mfma, dim3(8, 8), dim3(256), 0, stream, wTh, wTl,
                     v, beta, M);
  hipLaunchKernelGGL(hgemm_mfma, dim3(8, 100), dim3(256), 0, stream, x, wTh,
                     wTl, h);
  hipMemsetAsync(counts, 0, T_DIM * sizeof(int), stream);
  hipLaunchKernelGGL(scan_kernel, dim3(128), dim3(256), 0, stream, h, M, invn,
                     b, beta, out, counts);
  hipLaunchKernelGGL(finalize_kernel, dim3(1), dim3(64), 0, stream, counts,
                     out);
}